// Round 3
// baseline (457.944 us; speedup 1.0000x reference)
//
#include <hip/hip_runtime.h>

// EMA + gated blend, (B,L,C) = (32,4096,512) fp32.
// trend[l] = 0.7*x[l] + 0.3*trend[l-1];  out = g*x + (1-2g)*trend.
// Carry decays by 0.3/step -> parallelize the scan: each thread owns a
// chunk of L, warming the carry over an H-step halo seeded with x[l0-H].
// Halo error ~ 0.3^(H-1) ~ 2e-6 (H=12), far below the 5.4e-2 threshold.
//
// R1: CH=64 (16 waves/CU), NT stores, __launch_bounds__(256,4).
// R3: CHANNEL-PHASE SKEW. All chunk-streams advance in lockstep; with
// chunk boundaries at multiples of 64 rows (2KB each), every stream's
// instantaneous row index shares the same residue mod 64 -> concurrent
// accesses sit at 128KB stride hitting a small fixed subset of HBM
// channels (measured: 2.58 TB/s, 32% peak, VALUBusy 3.5% -> memory system
// at half rate, not latency). Skew each batch's chunk grid by
// o_b = (b*37) & 63 rows so concurrent residues span all channel groups.
// Chunk 0 absorbs [0, 64+o_b); last chunk ends at L.

constexpr int B   = 32;
constexpr int L   = 4096;
constexpr int C   = 512;
constexpr int CV  = C / 4;      // float4 groups along C = 128
constexpr int CH  = 64;         // nominal chunk length along L
constexpr int NCH = L / CH;     // 64 chunks
constexpr int H   = 12;         // halo warm-up length
constexpr float ALPHA = 0.7f;

typedef float f32x4 __attribute__((ext_vector_type(4)));

__device__ __forceinline__ void nt_store4(float4* p, const float4& v) {
    f32x4 w = {v.x, v.y, v.z, v.w};
    __builtin_nontemporal_store(w, reinterpret_cast<f32x4*>(p));
}

__device__ __forceinline__ float4 ema_step(float4 t, float4 xv, float a, float na) {
    float4 r;
    r.x = fmaf(a, xv.x, na * t.x);
    r.y = fmaf(a, xv.y, na * t.y);
    r.z = fmaf(a, xv.z, na * t.z);
    r.w = fmaf(a, xv.w, na * t.w);
    return r;
}

__global__ __launch_bounds__(256, 4) void STAR_47605417509306_kernel(
        const float4* __restrict__ x, const float* __restrict__ gate,
        float4* __restrict__ out) {
    const int tid   = blockIdx.x * blockDim.x + threadIdx.x;
    const int c4    = tid & (CV - 1);          // fastest-varying -> coalesced
    const int rest  = tid / CV;
    const int chunk = rest & (NCH - 1);
    const int b     = rest / NCH;

    float g = gate[0];
    g = fminf(fmaxf(g, 0.0f), 1.0f);
    const float a  = ALPHA;
    const float na = 1.0f - ALPHA;
    const float c2 = 1.0f - 2.0f * g;          // out = g*x + (1-2g)*t

    const int base = (b * L) * CV + c4;        // float4 index of (b, l=0, c4)
    const int ob   = (b * 37) & (CH - 1);      // per-batch phase skew [0,64)

    // Chunk m covers [l0, lend):
    //   m == 0      : [0, CH + ob)
    //   1..NCH-2    : [m*CH + ob, (m+1)*CH + ob)
    //   m == NCH-1  : [m*CH + ob, L)
    const int l0   = (chunk == 0) ? 0 : chunk * CH + ob;
    const int lend = (chunk == NCH - 1) ? L : (chunk + 1) * CH + ob;

    float4 t;
    int lstart;
    if (chunk == 0) {
        // Exact start: t_0 = x_0, and l=0 produces an output.
        t = x[base];
        float4 o;
        o.x = fmaf(g, t.x, c2 * t.x);
        o.y = fmaf(g, t.y, c2 * t.y);
        o.z = fmaf(g, t.z, c2 * t.z);
        o.w = fmaf(g, t.w, c2 * t.w);
        nt_store4(&out[base], o);
        lstart = 1;
    } else {
        // Halo warm-up: seed with x[l0-H], run H-1 recurrence steps.
        t = x[base + (l0 - H) * CV];
#pragma unroll
        for (int l = l0 - H + 1; l < l0; ++l) {
            float4 xv = x[base + l * CV];
            t = ema_step(t, xv, a, na);
        }
        lstart = l0;
    }

#pragma unroll 8
    for (int l = lstart; l < lend; ++l) {
        float4 xv = x[base + l * CV];
        t = ema_step(t, xv, a, na);
        float4 o;
        o.x = fmaf(g, xv.x, c2 * t.x);
        o.y = fmaf(g, xv.y, c2 * t.y);
        o.z = fmaf(g, xv.z, c2 * t.z);
        o.w = fmaf(g, xv.w, c2 * t.w);
        nt_store4(&out[base + l * CV], o);
    }
}

extern "C" void kernel_launch(void* const* d_in, const int* in_sizes, int n_in,
                              void* d_out, int out_size, void* d_ws, size_t ws_size,
                              hipStream_t stream) {
    const float4* x    = (const float4*)d_in[0];
    const float*  gate = (const float*)d_in[1];
    float4* out        = (float4*)d_out;

    const int total_threads = B * NCH * CV;    // 262144
    const int block = 256;
    const int grid  = total_threads / block;   // 1024
    STAR_47605417509306_kernel<<<grid, block, 0, stream>>>(x, gate, out);
}

// Round 4
// 456.434 us; speedup vs baseline: 1.0033x; 1.0033x over previous
//
#include <hip/hip_runtime.h>

// EMA + gated blend, (B,L,C) = (32,4096,512) fp32.
// trend[l] = 0.7*x[l] + 0.3*trend[l-1];  out = g*x + (1-2g)*trend.
// Carry decays by 0.3/step -> parallelize the scan: each thread owns a
// CH-row chunk of L, warming the carry over an H-step halo seeded with
// x[l0-H]. Halo error ~ 0.3^(H-1) ~ 2e-6, far below the 5.4e-2 threshold.
//
// R4: BURST DE-INTERLEAVE. R0-R3 (CH 128/64, NT stores, batch skew) all
// pinned at 165-167us / 2.56 TB/s with VGPR=32: the compiler kept only
// ~2 loads in flight and alternated load/store per row, so every load
// waitcnt drains the preceding store (vmcnt is in-order) and the DRAM bus
// ping-pongs read/write at fine grain. Restructure: register-stage BT=8
// rows (8-load burst -> 8 EMA+blend in place -> 8-store burst), double
// buffered (xa/xb) so the next load burst is in flight across the previous
// batch's compute+stores. Chunk 0 folds into the same 8x8 batching by
// seeding t=x[0] (fma(0.7,x,0.3x)=x to 1 ulp, so row 0 is reproduced).

constexpr int B   = 32;
constexpr int L   = 4096;
constexpr int C   = 512;
constexpr int CV  = C / 4;      // float4 groups along C = 128
constexpr int CH  = 64;         // chunk length along L
constexpr int NCH = L / CH;     // 64 chunks
constexpr int H   = 12;         // halo: seed + 11 recurrence steps
constexpr int BT  = 8;          // rows per register batch
constexpr int NB  = CH / BT;    // 8 batches per chunk
constexpr float ALPHA = 0.7f;

typedef float f32x4 __attribute__((ext_vector_type(4)));

__device__ __forceinline__ void nt_store4(float4* p, const float4& v) {
    f32x4 w = {v.x, v.y, v.z, v.w};
    __builtin_nontemporal_store(w, reinterpret_cast<f32x4*>(p));
}

__device__ __forceinline__ float4 ema_step(float4 t, float4 xv, float a, float na) {
    float4 r;
    r.x = fmaf(a, xv.x, na * t.x);
    r.y = fmaf(a, xv.y, na * t.y);
    r.z = fmaf(a, xv.z, na * t.z);
    r.w = fmaf(a, xv.w, na * t.w);
    return r;
}

__global__ __launch_bounds__(256, 4) void STAR_47605417509306_kernel(
        const float4* __restrict__ x, const float* __restrict__ gate,
        float4* __restrict__ out) {
    const int tid   = blockIdx.x * blockDim.x + threadIdx.x;
    const int c4    = tid & (CV - 1);          // fastest-varying -> coalesced
    const int rest  = tid / CV;
    const int chunk = rest & (NCH - 1);
    const int b     = rest / NCH;

    float g = gate[0];
    g = fminf(fmaxf(g, 0.0f), 1.0f);
    const float a  = ALPHA;
    const float na = 1.0f - ALPHA;
    const float c2 = 1.0f - 2.0f * g;          // out = g*x + (1-2g)*t

    const int base = (b * L) * CV + c4;        // float4 index of (b, l=0, c4)
    const int l0   = chunk * CH;

    // ---- carry seed ----
    float4 t;
    if (chunk == 0) {
        t = x[base];                           // ema_step reproduces x0 at l=0
    } else {
        float4 h[H];                           // burst the halo loads too
#pragma unroll
        for (int i = 0; i < H; ++i) h[i] = x[base + (l0 - H + i) * CV];
        t = h[0];
#pragma unroll
        for (int i = 1; i < H; ++i) t = ema_step(t, h[i], a, na);
    }

    // ---- main loop: 8 batches of 8 rows, double-buffered bursts ----
    float4 xa[BT], xb[BT];
#pragma unroll
    for (int i = 0; i < BT; ++i) xa[i] = x[base + (l0 + i) * CV];

#pragma unroll
    for (int bb = 0; bb < NB; bb += 2) {
        // prefetch batch bb+1 into xb (in flight across compute of bb)
#pragma unroll
        for (int i = 0; i < BT; ++i)
            xb[i] = x[base + (l0 + (bb + 1) * BT + i) * CV];

        // compute batch bb in place, then store burst
#pragma unroll
        for (int i = 0; i < BT; ++i) {
            t = ema_step(t, xa[i], a, na);
            float4 o;
            o.x = fmaf(g, xa[i].x, c2 * t.x);
            o.y = fmaf(g, xa[i].y, c2 * t.y);
            o.z = fmaf(g, xa[i].z, c2 * t.z);
            o.w = fmaf(g, xa[i].w, c2 * t.w);
            xa[i] = o;
        }
#pragma unroll
        for (int i = 0; i < BT; ++i)
            nt_store4(&out[base + (l0 + bb * BT + i) * CV], xa[i]);

        // prefetch batch bb+2 into xa (none on the last pair)
        if (bb + 2 < NB) {
#pragma unroll
            for (int i = 0; i < BT; ++i)
                xa[i] = x[base + (l0 + (bb + 2) * BT + i) * CV];
        }

        // compute batch bb+1 in place, then store burst
#pragma unroll
        for (int i = 0; i < BT; ++i) {
            t = ema_step(t, xb[i], a, na);
            float4 o;
            o.x = fmaf(g, xb[i].x, c2 * t.x);
            o.y = fmaf(g, xb[i].y, c2 * t.y);
            o.z = fmaf(g, xb[i].z, c2 * t.z);
            o.w = fmaf(g, xb[i].w, c2 * t.w);
            xb[i] = o;
        }
#pragma unroll
        for (int i = 0; i < BT; ++i)
            nt_store4(&out[base + (l0 + (bb + 1) * BT + i) * CV], xb[i]);
    }
}

extern "C" void kernel_launch(void* const* d_in, const int* in_sizes, int n_in,
                              void* d_out, int out_size, void* d_ws, size_t ws_size,
                              hipStream_t stream) {
    const float4* x    = (const float4*)d_in[0];
    const float*  gate = (const float*)d_in[1];
    float4* out        = (float4*)d_out;

    const int total_threads = B * NCH * CV;    // 262144
    const int block = 256;
    const int grid  = total_threads / block;   // 1024
    STAR_47605417509306_kernel<<<grid, block, 0, stream>>>(x, gate, out);
}

// Round 5
// 451.664 us; speedup vs baseline: 1.0139x; 1.0106x over previous
//
#include <hip/hip_runtime.h>

// EMA + gated blend, (B,L,C) = (32,4096,512) fp32.
// trend[l] = 0.7*x[l] + 0.3*trend[l-1];  out = g*x + (1-2g)*trend.
// Chunk-parallel scan: each thread owns CH rows of L, carry warmed over an
// H-step halo seeded with x[l0-H]; error ~0.3^(H-1) ~ 2e-6 << 5.4e-2.
//
// R5: NON-DRAINING STORE PIPELINE. R0-R4 all pinned at ~165us / 2.56 TB/s
// with VGPR=32..40: compiler emits load;wait;compute;store per row, and
// since vmcnt is one in-order counter, each load-wait forces the previous
// store's ack -> ~2.2us round-trip per row per wave (store ack under
// machine-wide write backpressure). Fix: 4-buffer rotation, prefetch
// distance 2, sched_barrier(0) pinning [loads k+2][compute k][stores k]
// so every load-wait is vmcnt(16) leaving the last two store batches
// outstanding. Stores never gate a wait; buffer reuse gives 2 iterations
// of slack before any store-source overwrite.

constexpr int B   = 32;
constexpr int L   = 4096;
constexpr int C   = 512;
constexpr int CV  = C / 4;      // float4 groups along C = 128
constexpr int CH  = 128;        // chunk length along L
constexpr int NCH = L / CH;     // 32 chunks
constexpr int H   = 12;         // halo: seed + 11 recurrence steps
constexpr int BT  = 4;          // rows per register batch
constexpr int NB  = CH / BT;    // 32 batches per chunk
constexpr float ALPHA = 0.7f;

typedef float f32x4 __attribute__((ext_vector_type(4)));

__device__ __forceinline__ void nt_store4(float4* p, const float4& v) {
    f32x4 w = {v.x, v.y, v.z, v.w};
    __builtin_nontemporal_store(w, reinterpret_cast<f32x4*>(p));
}

__device__ __forceinline__ float4 ema_step(float4 t, float4 xv, float a, float na) {
    float4 r;
    r.x = fmaf(a, xv.x, na * t.x);
    r.y = fmaf(a, xv.y, na * t.y);
    r.z = fmaf(a, xv.z, na * t.z);
    r.w = fmaf(a, xv.w, na * t.w);
    return r;
}

__global__ __launch_bounds__(256, 2) void STAR_47605417509306_kernel(
        const float4* __restrict__ x, const float* __restrict__ gate,
        float4* __restrict__ out) {
    const int tid   = blockIdx.x * blockDim.x + threadIdx.x;
    const int c4    = tid & (CV - 1);          // fastest-varying -> coalesced
    const int rest  = tid / CV;
    const int chunk = rest & (NCH - 1);
    const int b     = rest / NCH;

    float g = gate[0];
    g = fminf(fmaxf(g, 0.0f), 1.0f);
    const float a  = ALPHA;
    const float na = 1.0f - ALPHA;
    const float c2 = 1.0f - 2.0f * g;          // out = g*x + (1-2g)*t

    const int base = (b * L) * CV + c4;        // float4 index of (b, l=0, c4)
    const int l0   = chunk * CH;

    // ---- carry seed ----
    float4 t;
    if (chunk == 0) {
        t = x[base];                           // ema_step reproduces x0 at l=0
    } else {
        float4 h[H];
#pragma unroll
        for (int i = 0; i < H; ++i) h[i] = x[base + (l0 - H + i) * CV];
        t = h[0];
#pragma unroll
        for (int i = 1; i < H; ++i) t = ema_step(t, h[i], a, na);
    }

    float4 X0[BT], X1[BT], X2[BT], X3[BT];

#define LOADB(Xj, k)                                                   \
    do {                                                               \
        _Pragma("unroll")                                              \
        for (int i = 0; i < BT; ++i)                                   \
            Xj[i] = x[base + (l0 + (k) * BT + i) * CV];                \
    } while (0)

#define COMPB(Xj)                                                      \
    do {                                                               \
        _Pragma("unroll")                                              \
        for (int i = 0; i < BT; ++i) {                                 \
            t = ema_step(t, Xj[i], a, na);                             \
            float4 o;                                                  \
            o.x = fmaf(g, Xj[i].x, c2 * t.x);                          \
            o.y = fmaf(g, Xj[i].y, c2 * t.y);                          \
            o.z = fmaf(g, Xj[i].z, c2 * t.z);                          \
            o.w = fmaf(g, Xj[i].w, c2 * t.w);                          \
            Xj[i] = o;                                                 \
        }                                                              \
    } while (0)

#define STORB(Xj, k)                                                   \
    do {                                                               \
        _Pragma("unroll")                                              \
        for (int i = 0; i < BT; ++i)                                   \
            nt_store4(&out[base + (l0 + (k) * BT + i) * CV], Xj[i]);   \
    } while (0)

#define BODY(k, Xcur, Xpre)                                            \
    do {                                                               \
        if ((k) + 2 < NB) LOADB(Xpre, (k) + 2);                        \
        __builtin_amdgcn_sched_barrier(0);                             \
        COMPB(Xcur);                                                   \
        __builtin_amdgcn_sched_barrier(0);                             \
        STORB(Xcur, (k));                                              \
        __builtin_amdgcn_sched_barrier(0);                             \
    } while (0)

    // prologue: batches 0,1 in flight
    LOADB(X0, 0);
    LOADB(X1, 1);

    for (int kk = 0; kk < NB; kk += 4) {
        BODY(kk + 0, X0, X2);
        BODY(kk + 1, X1, X3);
        BODY(kk + 2, X2, X0);
        BODY(kk + 3, X3, X1);
    }

#undef LOADB
#undef COMPB
#undef STORB
#undef BODY
}

extern "C" void kernel_launch(void* const* d_in, const int* in_sizes, int n_in,
                              void* d_out, int out_size, void* d_ws, size_t ws_size,
                              hipStream_t stream) {
    const float4* x    = (const float4*)d_in[0];
    const float*  gate = (const float*)d_in[1];
    float4* out        = (float4*)d_out;

    const int total_threads = B * NCH * CV;    // 131072
    const int block = 256;
    const int grid  = total_threads / block;   // 512
    STAR_47605417509306_kernel<<<grid, block, 0, stream>>>(x, gate, out);
}